// Round 1
// baseline (3384.171 us; speedup 1.0000x reference)
//
#include <hip/hip_runtime.h>
#include <hip/hip_bf16.h>
#include <math.h>

// Problem constants (from setup_inputs): B=64, C=20, K=5, Q=15, D=2048
#define BATCH 64
#define NCLS  20
#define NS    100   // C*K supports per episode
#define NQ    300   // C*Q queries per episode
#define DIM   2048
#define MS    (BATCH * NS)   // 6400
#define MQ    (BATCH * NQ)   // 19200

// ---------------------------------------------------------------------------
// Tiled fp32 GEMM: Y[M][2048] = X[M][2048] @ W[2048][2048] + bias
// Tile 64x64, K-chunk 16, 256 threads, 4x4 micro-tile per thread.
// M is always a multiple of 64 here (6400 / 19200) -> no bounds checks.
// ---------------------------------------------------------------------------
__global__ __launch_bounds__(256) void gemm_xw(const float* __restrict__ X,
                                               const float* __restrict__ W,
                                               const float* __restrict__ bias,
                                               float* __restrict__ Y) {
  __shared__ float As[16][64];  // [k][m]
  __shared__ float Bs[16][64];  // [k][n]
  const int t    = threadIdx.x;
  const int row0 = blockIdx.x * 64;
  const int col0 = blockIdx.y * 64;

  const int am = t >> 2;          // 0..63 (A tile row)
  const int ak = (t & 3) * 4;     // 0,4,8,12 (A tile k)
  const int bk = t >> 4;          // 0..15 (B tile k)
  const int bn = (t & 15) * 4;    // 0..60 (B tile col)
  const int tm = (t >> 4) * 4;    // micro-tile origin
  const int tn = (t & 15) * 4;

  float acc[4][4] = {};

  for (int k0 = 0; k0 < DIM; k0 += 16) {
    float4 av = *(const float4*)(X + (size_t)(row0 + am) * DIM + k0 + ak);
    As[ak + 0][am] = av.x;
    As[ak + 1][am] = av.y;
    As[ak + 2][am] = av.z;
    As[ak + 3][am] = av.w;
    *(float4*)&Bs[bk][bn] =
        *(const float4*)(W + (size_t)(k0 + bk) * DIM + col0 + bn);
    __syncthreads();
#pragma unroll
    for (int k = 0; k < 16; ++k) {
      float4 a4 = *(const float4*)&As[k][tm];
      float4 b4 = *(const float4*)&Bs[k][tn];
      float av_[4] = {a4.x, a4.y, a4.z, a4.w};
      float bv_[4] = {b4.x, b4.y, b4.z, b4.w};
#pragma unroll
      for (int i = 0; i < 4; ++i)
#pragma unroll
        for (int j = 0; j < 4; ++j) acc[i][j] += av_[i] * bv_[j];
    }
    __syncthreads();
  }

  float4 bb = *(const float4*)(bias + col0 + tn);
  float bv_[4] = {bb.x, bb.y, bb.z, bb.w};
#pragma unroll
  for (int i = 0; i < 4; ++i) {
    float4 o;
    o.x = acc[i][0] + bv_[0];
    o.y = acc[i][1] + bv_[1];
    o.z = acc[i][2] + bv_[2];
    o.w = acc[i][3] + bv_[3];
    *(float4*)(Y + (size_t)(row0 + tm + i) * DIM + col0 + tn) = o;
  }
}

// ---------------------------------------------------------------------------
// inv_norm[row] = rsqrt(max(sum(s[row]^2), 1e-10))  for 6400 support rows
// ---------------------------------------------------------------------------
__global__ __launch_bounds__(256) void norm_kernel(const float* __restrict__ s,
                                                   float* __restrict__ inv_norm) {
  const int row = blockIdx.x;
  const float* p = s + (size_t)row * DIM;
  const int d0 = threadIdx.x * 8;  // 256*8 = 2048
  float4 a = *(const float4*)(p + d0);
  float4 b = *(const float4*)(p + d0 + 4);
  float sum = a.x * a.x + a.y * a.y + a.z * a.z + a.w * a.w +
              b.x * b.x + b.y * b.y + b.z * b.z + b.w * b.w;
#pragma unroll
  for (int off = 32; off; off >>= 1) sum += __shfl_down(sum, off, 64);
  __shared__ float red[4];
  if ((threadIdx.x & 63) == 0) red[threadIdx.x >> 6] = sum;
  __syncthreads();
  if (threadIdx.x == 0) {
    float tot = red[0] + red[1] + red[2] + red[3];
    inv_norm[row] = rsqrtf(fmaxf(tot, 1e-10f));
  }
}

// ---------------------------------------------------------------------------
// Batched sim GEMM: sim[b][m][n] = (q_b[m] . s_b[n]) * inv_norm[b*100+n]
// Per-batch M=300, N=100, K=2048. Tile 64x64 with bounds checks.
// grid = (2, 5, 64)
// ---------------------------------------------------------------------------
__global__ __launch_bounds__(256) void sim_kernel(const float* __restrict__ q,
                                                  const float* __restrict__ s,
                                                  const float* __restrict__ inv_norm,
                                                  float* __restrict__ sim) {
  __shared__ float As[16][64];  // [k][m]  (query)
  __shared__ float Bs[16][64];  // [k][n]  (support)
  const int t    = threadIdx.x;
  const int b    = blockIdx.z;
  const int row0 = blockIdx.y * 64;  // query row tile (0..256)
  const int col0 = blockIdx.x * 64;  // support col tile (0 or 64)

  const float* qb = q + (size_t)b * NQ * DIM;
  const float* sb = s + (size_t)b * NS * DIM;

  const int am = t >> 2;       // 0..63
  const int ak = (t & 3) * 4;  // 0,4,8,12
  const int tm = (t >> 4) * 4;
  const int tn = (t & 15) * 4;

  float acc[4][4] = {};

  for (int k0 = 0; k0 < DIM; k0 += 16) {
    // A tile: query rows (guard m < 300)
    float4 av = make_float4(0.f, 0.f, 0.f, 0.f);
    if (row0 + am < NQ)
      av = *(const float4*)(qb + (size_t)(row0 + am) * DIM + k0 + ak);
    As[ak + 0][am] = av.x;
    As[ak + 1][am] = av.y;
    As[ak + 2][am] = av.z;
    As[ak + 3][am] = av.w;
    // B tile: support rows transposed into [k][n] (guard n < 100)
    float4 bv = make_float4(0.f, 0.f, 0.f, 0.f);
    if (col0 + am < NS)
      bv = *(const float4*)(sb + (size_t)(col0 + am) * DIM + k0 + ak);
    Bs[ak + 0][am] = bv.x;
    Bs[ak + 1][am] = bv.y;
    Bs[ak + 2][am] = bv.z;
    Bs[ak + 3][am] = bv.w;
    __syncthreads();
#pragma unroll
    for (int k = 0; k < 16; ++k) {
      float4 a4 = *(const float4*)&As[k][tm];
      float4 b4 = *(const float4*)&Bs[k][tn];
      float av_[4] = {a4.x, a4.y, a4.z, a4.w};
      float bv_[4] = {b4.x, b4.y, b4.z, b4.w};
#pragma unroll
      for (int i = 0; i < 4; ++i)
#pragma unroll
        for (int j = 0; j < 4; ++j) acc[i][j] += av_[i] * bv_[j];
    }
    __syncthreads();
  }

#pragma unroll
  for (int i = 0; i < 4; ++i) {
    int m = row0 + tm + i;
    if (m >= NQ) continue;
#pragma unroll
    for (int j = 0; j < 4; ++j) {
      int n = col0 + tn + j;
      if (n >= NS) continue;
      sim[((size_t)b * NQ + m) * NS + n] = acc[i][j] * inv_norm[b * NS + n];
    }
  }
}

// ---------------------------------------------------------------------------
// Per query row: softmax over 100 supports, contract with one-hot labels,
// write probs[r][0..19] and pred[r] (as float). One wave per row, 4 rows/blk.
// ---------------------------------------------------------------------------
__global__ __launch_bounds__(256) void softmax_kernel(
    const float* __restrict__ sim, const float* __restrict__ onehot,
    float* __restrict__ out) {
  const int wave = threadIdx.x >> 6;
  const int lane = threadIdx.x & 63;
  const int r = blockIdx.x * 4 + wave;  // 0..19199
  const int b = r / NQ;

  const float* srow = sim + (size_t)r * NS;
  float v1 = srow[lane];
  float v2 = (lane < NS - 64) ? srow[lane + 64] : -INFINITY;

  float m = fmaxf(v1, v2);
#pragma unroll
  for (int off = 32; off; off >>= 1) m = fmaxf(m, __shfl_xor(m, off, 64));
  float e1 = expf(v1 - m);
  float e2 = (lane < NS - 64) ? expf(v2 - m) : 0.f;
  float ssum = e1 + e2;
#pragma unroll
  for (int off = 32; off; off >>= 1) ssum += __shfl_xor(ssum, off, 64);
  float inv = 1.0f / ssum;

  __shared__ float att[4][NS];
  __shared__ float pr[4][NCLS];
  att[wave][lane] = e1 * inv;
  if (lane < NS - 64) att[wave][lane + 64] = e2 * inv;
  __syncthreads();

  if (lane < NCLS) {
    const float* oh = onehot + ((size_t)b * NS) * NCLS + lane;
    float p = 0.f;
#pragma unroll 4
    for (int j = 0; j < NS; ++j) p += att[wave][j] * oh[(size_t)j * NCLS];
    out[(size_t)r * NCLS + lane] = p;
    pr[wave][lane] = p;
  }
  __syncthreads();

  if (lane == 0) {
    int best = 0;
    float bv = pr[wave][0];
    for (int c = 1; c < NCLS; ++c) {
      float v = pr[wave][c];
      if (v > bv) { bv = v; best = c; }  // strict > == np.argmax first-max
    }
    out[(size_t)MQ * NCLS + r] = (float)best;
  }
}

// ---------------------------------------------------------------------------
extern "C" void kernel_launch(void* const* d_in, const int* in_sizes, int n_in,
                              void* d_out, int out_size, void* d_ws,
                              size_t ws_size, hipStream_t stream) {
  const float* support = (const float*)d_in[0];  // [6400, 2048]
  const float* query   = (const float*)d_in[1];  // [19200, 2048]
  const float* onehot  = (const float*)d_in[2];  // [64, 100, 20]
  const float* W       = (const float*)d_in[3];  // [2048, 2048]
  const float* bias    = (const float*)d_in[4];  // [2048]

  float* ws       = (float*)d_ws;
  float* s        = ws;                        // 6400*2048
  float* q        = s + (size_t)MS * DIM;      // 19200*2048
  float* inv_norm = q + (size_t)MQ * DIM;      // 6400
  float* sim      = inv_norm + MS;             // 64*300*100

  gemm_xw<<<dim3(MS / 64, DIM / 64), 256, 0, stream>>>(support, W, bias, s);
  gemm_xw<<<dim3(MQ / 64, DIM / 64), 256, 0, stream>>>(query, W, bias, q);
  norm_kernel<<<MS, 256, 0, stream>>>(s, inv_norm);
  sim_kernel<<<dim3(2, 5, BATCH), 256, 0, stream>>>(q, s, inv_norm, sim);
  softmax_kernel<<<MQ / 4, 256, 0, stream>>>(sim, onehot, (float*)d_out);
}

// Round 3
// 1799.244 us; speedup vs baseline: 1.8809x; 1.8809x over previous
//
#include <hip/hip_runtime.h>
#include <hip/hip_bf16.h>
#include <math.h>

// Problem constants: B=64, C=20, K=5, Q=15, D=2048
#define BATCH 64
#define NCLS  20
#define NS    100   // C*K
#define NQ    300   // C*Q
#define DIM   2048
#define MS    (BATCH * NS)   // 6400
#define MQ    (BATCH * NQ)   // 19200

typedef __attribute__((ext_vector_type(8))) short frag_ab;   // 8 bf16 (4 VGPRs)
typedef __attribute__((ext_vector_type(4))) float frag_cd;   // 4 fp32 acc

union FAB { frag_ab f; unsigned u[4]; };

// round-to-nearest-even bf16 hi part, returned as fp32 bit pattern
__device__ __forceinline__ unsigned rne_hi(float x) {
  unsigned u = __float_as_uint(x);
  return (u + 0x7FFFu + ((u >> 16) & 1u)) & 0xFFFF0000u;
}
// truncated bf16 hi part; *hi gets fp32 bits, returns residual x - hi
__device__ __forceinline__ float trunc_hi(float x, unsigned* hi) {
  unsigned h = __float_as_uint(x) & 0xFFFF0000u;
  *hi = h;
  return x - __uint_as_float(h);
}
// 3-level truncation split of a pair (x,y) -> three packed bf16x2 words
__device__ __forceinline__ void split3_pair(float x, float y, unsigned& p1,
                                            unsigned& p2, unsigned& p3) {
  unsigned hx1, hy1, hx2, hy2;
  float rx1 = trunc_hi(x, &hx1), ry1 = trunc_hi(y, &hy1);
  float rx2 = trunc_hi(rx1, &hx2), ry2 = trunc_hi(ry1, &hy2);
  p1 = (hx1 >> 16) | (hy1 & 0xFFFF0000u);
  p2 = (hx2 >> 16) | (hy2 & 0xFFFF0000u);
  p3 = (__float_as_uint(rx2) >> 16) | (__float_as_uint(ry2) & 0xFFFF0000u);
}

#define GLL16(g, l)                                                            \
  __builtin_amdgcn_global_load_lds(                                            \
      (const __attribute__((address_space(1))) void*)(g),                      \
      (__attribute__((address_space(3))) void*)(l), 16, 0, 0)

// ---------------------------------------------------------------------------
// W [k][n] fp32 -> W1/W2/W3 [n][k] bf16, 3-level RNE split (hi+mid+lo ~2^-24)
// grid (32,32), 64x64 tile transpose via LDS.
// ---------------------------------------------------------------------------
__global__ __launch_bounds__(256) void wsplit3(const float* __restrict__ W,
                                               unsigned short* __restrict__ W1,
                                               unsigned short* __restrict__ W2,
                                               unsigned short* __restrict__ W3) {
  __shared__ float T[64][65];
  const int k0 = blockIdx.x * 64, n0 = blockIdx.y * 64;
  const int r = threadIdx.x >> 4, c = (threadIdx.x & 15) * 4;
#pragma unroll
  for (int p = 0; p < 4; ++p) {
    float4 v = *(const float4*)&W[(size_t)(k0 + p * 16 + r) * DIM + n0 + c];
    T[p * 16 + r][c + 0] = v.x;
    T[p * 16 + r][c + 1] = v.y;
    T[p * 16 + r][c + 2] = v.z;
    T[p * 16 + r][c + 3] = v.w;
  }
  __syncthreads();
#pragma unroll
  for (int p = 0; p < 4; ++p) {
    int n = p * 16 + r;
    ushort4 o1, o2, o3;
    unsigned short* d1 = (unsigned short*)&o1;
    unsigned short* d2 = (unsigned short*)&o2;
    unsigned short* d3 = (unsigned short*)&o3;
#pragma unroll
    for (int qq = 0; qq < 4; ++qq) {
      float x = T[c + qq][n];
      unsigned u1 = rne_hi(x);
      float r1 = x - __uint_as_float(u1);
      unsigned u2 = rne_hi(r1);
      float r2 = r1 - __uint_as_float(u2);
      unsigned u3 = rne_hi(r2);
      d1[qq] = (unsigned short)(u1 >> 16);
      d2[qq] = (unsigned short)(u2 >> 16);
      d3[qq] = (unsigned short)(u3 >> 16);
    }
    *(ushort4*)&W1[(size_t)(n0 + n) * DIM + k0 + c] = o1;
    *(ushort4*)&W2[(size_t)(n0 + n) * DIM + k0 + c] = o2;
    *(ushort4*)&W3[(size_t)(n0 + n) * DIM + k0 + c] = o3;
  }
}

// ---------------------------------------------------------------------------
// MFMA 3-way-split GEMM: Y[M][2048] = X @ W + bias, fp32-class accuracy.
// 128x128 tile, BK=32, 4 waves 2x2, 16x16x32_bf16.
// 6 MFMAs per tile pair: (1,1)(1,2)(2,1)(2,2)(1,3)(3,1); dropped terms are
// below fp32 accumulation noise. A staged fp32 + split in regs (truncation);
// W pre-split [n][k] (RNE) so B frags are single ds_read_b128.
// grid: blockIdx.x = col tile (fast dim -> W + X tiles stay L2/L3 resident)
// ---------------------------------------------------------------------------
__global__ __launch_bounds__(256) void gemm_mfma3(
    const float* __restrict__ X, const unsigned short* __restrict__ W1,
    const unsigned short* __restrict__ W2,
    const unsigned short* __restrict__ W3, const float* __restrict__ bias,
    float* __restrict__ Y) {
  __shared__ __align__(16) float          As[4][2][128][4];  // [kq][h][m][4k] 16KB
  __shared__ __align__(16) unsigned short B1[4][128][8];     // [kq][n][8k] 8KB
  __shared__ __align__(16) unsigned short B2[4][128][8];
  __shared__ __align__(16) unsigned short B3[4][128][8];

  const int tid = threadIdx.x;
  const int w = tid >> 6, lane = tid & 63;
  const int ml = lane & 15, kq = lane >> 4;
  const int wm = (w >> 1) * 64, wn = (w & 1) * 64;
  const int col0 = blockIdx.x * 128, row0 = blockIdx.y * 128;

  frag_cd acc[4][4];
#pragma unroll
  for (int i = 0; i < 4; ++i)
#pragma unroll
    for (int j = 0; j < 4; ++j)
#pragma unroll
      for (int r = 0; r < 4; ++r) acc[i][j][r] = 0.f;

  for (int k0 = 0; k0 < DIM; k0 += 32) {
    // ---- stage A (fp32): wave w covers kq=w ----
#pragma unroll
    for (int h = 0; h < 2; ++h)
#pragma unroll
      for (int mh = 0; mh < 2; ++mh) {
        const float* g =
            X + (size_t)(row0 + mh * 64 + lane) * DIM + k0 + w * 8 + h * 4;
        GLL16(g, &As[w][h][mh * 64][0]);
      }
    // ---- stage B (3 bf16 splits): wave w covers kq=w ----
#pragma unroll
    for (int nh = 0; nh < 2; ++nh) {
      const size_t off = (size_t)(col0 + nh * 64 + lane) * DIM + k0 + w * 8;
      GLL16(W1 + off, &B1[w][nh * 64][0]);
      GLL16(W2 + off, &B2[w][nh * 64][0]);
      GLL16(W3 + off, &B3[w][nh * 64][0]);
    }
    __syncthreads();

    // ---- A frags: fp32 -> 3-level truncation split in registers ----
    FAB a1[4], a2[4], a3[4];
#pragma unroll
    for (int i = 0; i < 4; ++i) {
      int m = wm + i * 16 + ml;
      float4 f0 = *(const float4*)&As[kq][0][m][0];  // k = kq*8 + 0..3
      float4 f1 = *(const float4*)&As[kq][1][m][0];  // k = kq*8 + 4..7
      split3_pair(f0.x, f0.y, a1[i].u[0], a2[i].u[0], a3[i].u[0]);
      split3_pair(f0.z, f0.w, a1[i].u[1], a2[i].u[1], a3[i].u[1]);
      split3_pair(f1.x, f1.y, a1[i].u[2], a2[i].u[2], a3[i].u[2]);
      split3_pair(f1.z, f1.w, a1[i].u[3], a2[i].u[3], a3[i].u[3]);
    }
    // ---- B frags + 6-term MFMA ----
#pragma unroll
    for (int j = 0; j < 4; ++j) {
      int n = wn + j * 16 + ml;
      FAB b1, b2, b3;
      *(uint4*)&b1.u[0] = *(const uint4*)&B1[kq][n][0];
      *(uint4*)&b2.u[0] = *(const uint4*)&B2[kq][n][0];
      *(uint4*)&b3.u[0] = *(const uint4*)&B3[kq][n][0];
#pragma unroll
      for (int i = 0; i < 4; ++i) {
        acc[i][j] = __builtin_amdgcn_mfma_f32_16x16x32_bf16(a1[i].f, b1.f,
                                                            acc[i][j], 0, 0, 0);
        acc[i][j] = __builtin_amdgcn_mfma_f32_16x16x32_bf16(a1[i].f, b2.f,
                                                            acc[i][j], 0, 0, 0);
        acc[i][j] = __builtin_amdgcn_mfma_f32_16x16x32_bf16(a2[i].f, b1.f,
                                                            acc[i][j], 0, 0, 0);
        acc[i][j] = __builtin_amdgcn_mfma_f32_16x16x32_bf16(a2[i].f, b2.f,
                                                            acc[i][j], 0, 0, 0);
        acc[i][j] = __builtin_amdgcn_mfma_f32_16x16x32_bf16(a1[i].f, b3.f,
                                                            acc[i][j], 0, 0, 0);
        acc[i][j] = __builtin_amdgcn_mfma_f32_16x16x32_bf16(a3[i].f, b1.f,
                                                            acc[i][j], 0, 0, 0);
      }
    }
    __syncthreads();
  }

  // ---- epilogue: C/D layout col=lane&15, row=(lane>>4)*4+reg ----
#pragma unroll
  for (int j = 0; j < 4; ++j) {
    int col = col0 + wn + j * 16 + ml;
    float bv = bias[col];
#pragma unroll
    for (int i = 0; i < 4; ++i) {
      int rowb = row0 + wm + i * 16 + kq * 4;
#pragma unroll
      for (int r = 0; r < 4; ++r)
        Y[(size_t)(rowb + r) * DIM + col] = acc[i][j][r] + bv;
    }
  }
}

// ---------------------------------------------------------------------------
// Fallback fp32 GEMM (proven R1 path, used only if ws_size is too small)
// ---------------------------------------------------------------------------
__global__ __launch_bounds__(256) void gemm_xw(const float* __restrict__ X,
                                               const float* __restrict__ W,
                                               const float* __restrict__ bias,
                                               float* __restrict__ Y) {
  __shared__ float As[16][64];
  __shared__ float Bs[16][64];
  const int t = threadIdx.x;
  const int row0 = blockIdx.x * 64;
  const int col0 = blockIdx.y * 64;
  const int am = t >> 2, ak = (t & 3) * 4;
  const int bk = t >> 4, bn = (t & 15) * 4;
  const int tm = (t >> 4) * 4, tn = (t & 15) * 4;
  float acc[4][4] = {};
  for (int k0 = 0; k0 < DIM; k0 += 16) {
    float4 av = *(const float4*)(X + (size_t)(row0 + am) * DIM + k0 + ak);
    As[ak + 0][am] = av.x;
    As[ak + 1][am] = av.y;
    As[ak + 2][am] = av.z;
    As[ak + 3][am] = av.w;
    *(float4*)&Bs[bk][bn] =
        *(const float4*)(W + (size_t)(k0 + bk) * DIM + col0 + bn);
    __syncthreads();
#pragma unroll
    for (int k = 0; k < 16; ++k) {
      float4 a4 = *(const float4*)&As[k][tm];
      float4 b4 = *(const float4*)&Bs[k][tn];
      float av_[4] = {a4.x, a4.y, a4.z, a4.w};
      float bv_[4] = {b4.x, b4.y, b4.z, b4.w};
#pragma unroll
      for (int i = 0; i < 4; ++i)
#pragma unroll
        for (int j = 0; j < 4; ++j) acc[i][j] += av_[i] * bv_[j];
    }
    __syncthreads();
  }
  float4 bb = *(const float4*)(bias + col0 + tn);
  float bv_[4] = {bb.x, bb.y, bb.z, bb.w};
#pragma unroll
  for (int i = 0; i < 4; ++i) {
    float4 o;
    o.x = acc[i][0] + bv_[0];
    o.y = acc[i][1] + bv_[1];
    o.z = acc[i][2] + bv_[2];
    o.w = acc[i][3] + bv_[3];
    *(float4*)(Y + (size_t)(row0 + tm + i) * DIM + col0 + tn) = o;
  }
}

// ---------------------------------------------------------------------------
// inv_norm[row] = rsqrt(max(sum(s^2), 1e-10))
// ---------------------------------------------------------------------------
__global__ __launch_bounds__(256) void norm_kernel(const float* __restrict__ s,
                                                   float* __restrict__ inv_norm) {
  const int row = blockIdx.x;
  const float* p = s + (size_t)row * DIM;
  const int d0 = threadIdx.x * 8;
  float4 a = *(const float4*)(p + d0);
  float4 b = *(const float4*)(p + d0 + 4);
  float sum = a.x * a.x + a.y * a.y + a.z * a.z + a.w * a.w +
              b.x * b.x + b.y * b.y + b.z * b.z + b.w * b.w;
#pragma unroll
  for (int off = 32; off; off >>= 1) sum += __shfl_down(sum, off, 64);
  __shared__ float red[4];
  if ((threadIdx.x & 63) == 0) red[threadIdx.x >> 6] = sum;
  __syncthreads();
  if (threadIdx.x == 0) {
    float tot = red[0] + red[1] + red[2] + red[3];
    inv_norm[row] = rsqrtf(fmaxf(tot, 1e-10f));
  }
}

// ---------------------------------------------------------------------------
// sim[b][m][n] = (q_b[m] . s_b[n]) * inv_norm[b*100+n]
// ---------------------------------------------------------------------------
__global__ __launch_bounds__(256) void sim_kernel(const float* __restrict__ q,
                                                  const float* __restrict__ s,
                                                  const float* __restrict__ inv_norm,
                                                  float* __restrict__ sim) {
  __shared__ float As[16][64];
  __shared__ float Bs[16][64];
  const int t = threadIdx.x;
  const int b = blockIdx.z;
  const int row0 = blockIdx.y * 64;
  const int col0 = blockIdx.x * 64;
  const float* qb = q + (size_t)b * NQ * DIM;
  const float* sb = s + (size_t)b * NS * DIM;
  const int am = t >> 2, ak = (t & 3) * 4;
  const int tm = (t >> 4) * 4, tn = (t & 15) * 4;
  float acc[4][4] = {};
  for (int k0 = 0; k0 < DIM; k0 += 16) {
    float4 av = make_float4(0.f, 0.f, 0.f, 0.f);
    if (row0 + am < NQ)
      av = *(const float4*)(qb + (size_t)(row0 + am) * DIM + k0 + ak);
    As[ak + 0][am] = av.x;
    As[ak + 1][am] = av.y;
    As[ak + 2][am] = av.z;
    As[ak + 3][am] = av.w;
    float4 bv = make_float4(0.f, 0.f, 0.f, 0.f);
    if (col0 + am < NS)
      bv = *(const float4*)(sb + (size_t)(col0 + am) * DIM + k0 + ak);
    Bs[ak + 0][am] = bv.x;
    Bs[ak + 1][am] = bv.y;
    Bs[ak + 2][am] = bv.z;
    Bs[ak + 3][am] = bv.w;
    __syncthreads();
#pragma unroll
    for (int k = 0; k < 16; ++k) {
      float4 a4 = *(const float4*)&As[k][tm];
      float4 b4 = *(const float4*)&Bs[k][tn];
      float av_[4] = {a4.x, a4.y, a4.z, a4.w};
      float bv_[4] = {b4.x, b4.y, b4.z, b4.w};
#pragma unroll
      for (int i = 0; i < 4; ++i)
#pragma unroll
        for (int j = 0; j < 4; ++j) acc[i][j] += av_[i] * bv_[j];
    }
    __syncthreads();
  }
#pragma unroll
  for (int i = 0; i < 4; ++i) {
    int m = row0 + tm + i;
    if (m >= NQ) continue;
#pragma unroll
    for (int j = 0; j < 4; ++j) {
      int n = col0 + tn + j;
      if (n >= NS) continue;
      sim[((size_t)b * NQ + m) * NS + n] = acc[i][j] * inv_norm[b * NS + n];
    }
  }
}

// ---------------------------------------------------------------------------
// softmax(100) -> one-hot contract (20) -> probs + argmax(pred as float)
// ---------------------------------------------------------------------------
__global__ __launch_bounds__(256) void softmax_kernel(
    const float* __restrict__ sim, const float* __restrict__ onehot,
    float* __restrict__ out) {
  const int wave = threadIdx.x >> 6;
  const int lane = threadIdx.x & 63;
  const int r = blockIdx.x * 4 + wave;
  const int b = r / NQ;
  const float* srow = sim + (size_t)r * NS;
  float v1 = srow[lane];
  float v2 = (lane < NS - 64) ? srow[lane + 64] : -INFINITY;
  float m = fmaxf(v1, v2);
#pragma unroll
  for (int off = 32; off; off >>= 1) m = fmaxf(m, __shfl_xor(m, off, 64));
  float e1 = expf(v1 - m);
  float e2 = (lane < NS - 64) ? expf(v2 - m) : 0.f;
  float ssum = e1 + e2;
#pragma unroll
  for (int off = 32; off; off >>= 1) ssum += __shfl_xor(ssum, off, 64);
  float inv = 1.0f / ssum;
  __shared__ float att[4][NS];
  __shared__ float pr[4][NCLS];
  att[wave][lane] = e1 * inv;
  if (lane < NS - 64) att[wave][lane + 64] = e2 * inv;
  __syncthreads();
  if (lane < NCLS) {
    const float* oh = onehot + ((size_t)b * NS) * NCLS + lane;
    float p = 0.f;
#pragma unroll 4
    for (int j = 0; j < NS; ++j) p += att[wave][j] * oh[(size_t)j * NCLS];
    out[(size_t)r * NCLS + lane] = p;
    pr[wave][lane] = p;
  }
  __syncthreads();
  if (lane == 0) {
    int best = 0;
    float bv = pr[wave][0];
    for (int c = 1; c < NCLS; ++c) {
      float v = pr[wave][c];
      if (v > bv) { bv = v; best = c; }
    }
    out[(size_t)MQ * NCLS + r] = (float)best;
  }
}

// ---------------------------------------------------------------------------
extern "C" void kernel_launch(void* const* d_in, const int* in_sizes, int n_in,
                              void* d_out, int out_size, void* d_ws,
                              size_t ws_size, hipStream_t stream) {
  const float* support = (const float*)d_in[0];
  const float* query   = (const float*)d_in[1];
  const float* onehot  = (const float*)d_in[2];
  const float* W       = (const float*)d_in[3];
  const float* bias    = (const float*)d_in[4];

  char* wsb = (char*)d_ws;
  float* s = (float*)wsb;                       // 6400*2048*4  = 52,428,800
  float* q = (float*)(wsb + (size_t)52428800);  // 19200*2048*4 = 157,286,400

  // s+q end at 209,715,200; W1/W2/W3 bf16 splits 8,388,608 each
  const size_t FAST3 = 234881024;  // 224 MiB

  if (ws_size >= FAST3) {
    unsigned short* W1 = (unsigned short*)(wsb + (size_t)209715200);
    unsigned short* W2 = (unsigned short*)(wsb + (size_t)218103808);
    unsigned short* W3 = (unsigned short*)(wsb + (size_t)226492416);
    // sim + inv_norm alias the W1 region (splits dead after the gemms)
    float* sim      = (float*)(wsb + (size_t)209715200);
    float* inv_norm = (float*)(wsb + (size_t)209715200 + (size_t)MQ * NS * 4);

    wsplit3<<<dim3(DIM / 64, DIM / 64), 256, 0, stream>>>(W, W1, W2, W3);
    gemm_mfma3<<<dim3(DIM / 128, MS / 128), 256, 0, stream>>>(support, W1, W2,
                                                              W3, bias, s);
    gemm_mfma3<<<dim3(DIM / 128, MQ / 128), 256, 0, stream>>>(query, W1, W2,
                                                              W3, bias, q);
    norm_kernel<<<MS, 256, 0, stream>>>(s, inv_norm);
    sim_kernel<<<dim3(2, 5, BATCH), 256, 0, stream>>>(q, s, inv_norm, sim);
    softmax_kernel<<<MQ / 4, 256, 0, stream>>>(sim, onehot, (float*)d_out);
  } else {
    // proven R1 fallback (fits in 217.5 MB)
    float* inv_norm = q + (size_t)MQ * DIM;
    float* sim      = inv_norm + MS;
    gemm_xw<<<dim3(MS / 64, DIM / 64), 256, 0, stream>>>(support, W, bias, s);
    gemm_xw<<<dim3(MQ / 64, DIM / 64), 256, 0, stream>>>(query, W, bias, q);
    norm_kernel<<<MS, 256, 0, stream>>>(s, inv_norm);
    sim_kernel<<<dim3(2, 5, BATCH), 256, 0, stream>>>(q, s, inv_norm, sim);
    softmax_kernel<<<MQ / 4, 256, 0, stream>>>(sim, onehot, (float*)d_out);
  }
}

// Round 4
// 1622.983 us; speedup vs baseline: 2.0852x; 1.1086x over previous
//
#include <hip/hip_runtime.h>
#include <hip/hip_bf16.h>
#include <math.h>

// Problem constants: B=64, C=20, K=5, Q=15, D=2048
#define BATCH 64
#define NCLS  20
#define NS    100   // C*K
#define NQ    300   // C*Q
#define DIM   2048
#define MS    (BATCH * NS)   // 6400
#define MQ    (BATCH * NQ)   // 19200

typedef __attribute__((ext_vector_type(8))) short frag_ab;   // 8 bf16 (4 VGPRs)
typedef __attribute__((ext_vector_type(4))) float frag_cd;   // 4 fp32 acc

union FAB { frag_ab f; unsigned u[4]; };

// round-to-nearest-even bf16 hi part, returned as fp32 bit pattern
__device__ __forceinline__ unsigned rne_hi(float x) {
  unsigned u = __float_as_uint(x);
  return (u + 0x7FFFu + ((u >> 16) & 1u)) & 0xFFFF0000u;
}

// 2-level RNE split of pair (x,y): x ~= x1 + x2 with |residual| <= 2^-18|x|.
// p1/p2 are packed bf16x2 words (low short = x, high short = y) matching the
// MFMA A-operand layout (k even in low half).
__device__ __forceinline__ void split2rn(float x, float y, unsigned& p1,
                                         unsigned& p2) {
  union { __hip_bfloat162 h; unsigned u; } c1, c2;
  c1.h = __float22bfloat162_rn(make_float2(x, y));
  p1 = c1.u;
  float rx = x - __uint_as_float(c1.u << 16);
  float ry = y - __uint_as_float(c1.u & 0xFFFF0000u);
  c2.h = __float22bfloat162_rn(make_float2(rx, ry));
  p2 = c2.u;
}

#define GLL16(g, l)                                                            \
  __builtin_amdgcn_global_load_lds(                                            \
      (const __attribute__((address_space(1))) void*)(g),                      \
      (__attribute__((address_space(3))) void*)(l), 16, 0, 0)

// ---------------------------------------------------------------------------
// W [k][n] fp32 -> W1/W2/W3 [n][k] bf16, 3-level RNE split (hi+mid+lo ~2^-27)
// grid (32,32), 64x64 tile transpose via LDS.  (unchanged from R3 - proven)
// ---------------------------------------------------------------------------
__global__ __launch_bounds__(256) void wsplit3(const float* __restrict__ W,
                                               unsigned short* __restrict__ W1,
                                               unsigned short* __restrict__ W2,
                                               unsigned short* __restrict__ W3) {
  __shared__ float T[64][65];
  const int k0 = blockIdx.x * 64, n0 = blockIdx.y * 64;
  const int r = threadIdx.x >> 4, c = (threadIdx.x & 15) * 4;
#pragma unroll
  for (int p = 0; p < 4; ++p) {
    float4 v = *(const float4*)&W[(size_t)(k0 + p * 16 + r) * DIM + n0 + c];
    T[p * 16 + r][c + 0] = v.x;
    T[p * 16 + r][c + 1] = v.y;
    T[p * 16 + r][c + 2] = v.z;
    T[p * 16 + r][c + 3] = v.w;
  }
  __syncthreads();
#pragma unroll
  for (int p = 0; p < 4; ++p) {
    int n = p * 16 + r;
    ushort4 o1, o2, o3;
    unsigned short* d1 = (unsigned short*)&o1;
    unsigned short* d2 = (unsigned short*)&o2;
    unsigned short* d3 = (unsigned short*)&o3;
#pragma unroll
    for (int qq = 0; qq < 4; ++qq) {
      float x = T[c + qq][n];
      unsigned u1 = rne_hi(x);
      float r1 = x - __uint_as_float(u1);
      unsigned u2 = rne_hi(r1);
      float r2 = r1 - __uint_as_float(u2);
      unsigned u3 = rne_hi(r2);
      d1[qq] = (unsigned short)(u1 >> 16);
      d2[qq] = (unsigned short)(u2 >> 16);
      d3[qq] = (unsigned short)(u3 >> 16);
    }
    *(ushort4*)&W1[(size_t)(n0 + n) * DIM + k0 + c] = o1;
    *(ushort4*)&W2[(size_t)(n0 + n) * DIM + k0 + c] = o2;
    *(ushort4*)&W3[(size_t)(n0 + n) * DIM + k0 + c] = o3;
  }
}

// ---------------------------------------------------------------------------
// MFMA split GEMM, 5 terms: Y = X @ W + bias, fp32-class accuracy.
// Block tile 128(M) x 256(N), BK=32, 4 waves 2x2 over the 128x128 half,
// looping 2 column halves (amortizes A-split VALU + barrier over 160 MFMAs).
// A: 2-level RNE split in registers (res ~2^-18, sign-symmetric).
// B: pre-split W1/W2/W3 [n][k].  Terms a1b1,a1b2,a2b1,a2b2,a1b3.
// ---------------------------------------------------------------------------
__global__ __launch_bounds__(256, 2) void gemm_mfma5(
    const float* __restrict__ X, const unsigned short* __restrict__ W1,
    const unsigned short* __restrict__ W2,
    const unsigned short* __restrict__ W3, const float* __restrict__ bias,
    float* __restrict__ Y) {
  __shared__ __align__(16) float          As[4][2][128][4];  // 16KB
  __shared__ __align__(16) unsigned short B1[4][256][8];     // 16KB
  __shared__ __align__(16) unsigned short B2[4][256][8];     // 16KB
  __shared__ __align__(16) unsigned short B3[4][256][8];     // 16KB

  const int tid = threadIdx.x;
  const int w = tid >> 6, lane = tid & 63;
  const int ml = lane & 15, kq = lane >> 4;
  const int wm = (w >> 1) * 64, wn = (w & 1) * 64;
  const int col0 = blockIdx.x * 256, row0 = blockIdx.y * 128;

  frag_cd acc[2][4][4];
#pragma unroll
  for (int h = 0; h < 2; ++h)
#pragma unroll
    for (int i = 0; i < 4; ++i)
#pragma unroll
      for (int j = 0; j < 4; ++j)
#pragma unroll
        for (int r = 0; r < 4; ++r) acc[h][i][j][r] = 0.f;

  for (int k0 = 0; k0 < DIM; k0 += 32) {
    // ---- stage A (fp32): wave w covers kq=w ----
#pragma unroll
    for (int h = 0; h < 2; ++h)
#pragma unroll
      for (int mh = 0; mh < 2; ++mh) {
        const float* g =
            X + (size_t)(row0 + mh * 64 + lane) * DIM + k0 + w * 8 + h * 4;
        GLL16(g, &As[w][h][mh * 64][0]);
      }
    // ---- stage B (3 splits x 256 cols): wave w covers kq=w ----
#pragma unroll
    for (int t = 0; t < 4; ++t) {
      const size_t off = (size_t)(col0 + t * 64 + lane) * DIM + k0 + w * 8;
      GLL16(W1 + off, &B1[w][t * 64][0]);
      GLL16(W2 + off, &B2[w][t * 64][0]);
      GLL16(W3 + off, &B3[w][t * 64][0]);
    }
    __syncthreads();

    // ---- A frags: fp32 -> 2-level RNE split (once per k-tile) ----
    FAB a1[4], a2[4];
#pragma unroll
    for (int i = 0; i < 4; ++i) {
      int m = wm + i * 16 + ml;
      float4 f0 = *(const float4*)&As[kq][0][m][0];  // k = kq*8 + 0..3
      float4 f1 = *(const float4*)&As[kq][1][m][0];  // k = kq*8 + 4..7
      split2rn(f0.x, f0.y, a1[i].u[0], a2[i].u[0]);
      split2rn(f0.z, f0.w, a1[i].u[1], a2[i].u[1]);
      split2rn(f1.x, f1.y, a1[i].u[2], a2[i].u[2]);
      split2rn(f1.z, f1.w, a1[i].u[3], a2[i].u[3]);
    }
    // ---- 2 column halves x 16 frag-pairs x 5 MFMA terms ----
#pragma unroll
    for (int nh = 0; nh < 2; ++nh) {
#pragma unroll
      for (int j = 0; j < 4; ++j) {
        int n = nh * 128 + wn + j * 16 + ml;
        FAB b1, b2, b3;
        *(uint4*)&b1.u[0] = *(const uint4*)&B1[kq][n][0];
        *(uint4*)&b2.u[0] = *(const uint4*)&B2[kq][n][0];
        *(uint4*)&b3.u[0] = *(const uint4*)&B3[kq][n][0];
#pragma unroll
        for (int i = 0; i < 4; ++i) {
          acc[nh][i][j] = __builtin_amdgcn_mfma_f32_16x16x32_bf16(
              a1[i].f, b1.f, acc[nh][i][j], 0, 0, 0);
          acc[nh][i][j] = __builtin_amdgcn_mfma_f32_16x16x32_bf16(
              a1[i].f, b2.f, acc[nh][i][j], 0, 0, 0);
          acc[nh][i][j] = __builtin_amdgcn_mfma_f32_16x16x32_bf16(
              a2[i].f, b1.f, acc[nh][i][j], 0, 0, 0);
          acc[nh][i][j] = __builtin_amdgcn_mfma_f32_16x16x32_bf16(
              a2[i].f, b2.f, acc[nh][i][j], 0, 0, 0);
          acc[nh][i][j] = __builtin_amdgcn_mfma_f32_16x16x32_bf16(
              a1[i].f, b3.f, acc[nh][i][j], 0, 0, 0);
        }
      }
    }
    __syncthreads();
  }

  // ---- epilogue: C/D layout col=lane&15, row=(lane>>4)*4+reg ----
#pragma unroll
  for (int nh = 0; nh < 2; ++nh)
#pragma unroll
    for (int j = 0; j < 4; ++j) {
      int col = col0 + nh * 128 + wn + j * 16 + ml;
      float bv = bias[col];
#pragma unroll
      for (int i = 0; i < 4; ++i) {
        int rowb = row0 + wm + i * 16 + kq * 4;
#pragma unroll
        for (int r = 0; r < 4; ++r)
          Y[(size_t)(rowb + r) * DIM + col] = acc[nh][i][j][r] + bv;
      }
    }
}

// ---------------------------------------------------------------------------
// Fallback fp32 GEMM (proven R1 path, used only if ws_size is too small)
// ---------------------------------------------------------------------------
__global__ __launch_bounds__(256) void gemm_xw(const float* __restrict__ X,
                                               const float* __restrict__ W,
                                               const float* __restrict__ bias,
                                               float* __restrict__ Y) {
  __shared__ float As[16][64];
  __shared__ float Bs[16][64];
  const int t = threadIdx.x;
  const int row0 = blockIdx.x * 64;
  const int col0 = blockIdx.y * 64;
  const int am = t >> 2, ak = (t & 3) * 4;
  const int bk = t >> 4, bn = (t & 15) * 4;
  const int tm = (t >> 4) * 4, tn = (t & 15) * 4;
  float acc[4][4] = {};
  for (int k0 = 0; k0 < DIM; k0 += 16) {
    float4 av = *(const float4*)(X + (size_t)(row0 + am) * DIM + k0 + ak);
    As[ak + 0][am] = av.x;
    As[ak + 1][am] = av.y;
    As[ak + 2][am] = av.z;
    As[ak + 3][am] = av.w;
    *(float4*)&Bs[bk][bn] =
        *(const float4*)(W + (size_t)(k0 + bk) * DIM + col0 + bn);
    __syncthreads();
#pragma unroll
    for (int k = 0; k < 16; ++k) {
      float4 a4 = *(const float4*)&As[k][tm];
      float4 b4 = *(const float4*)&Bs[k][tn];
      float av_[4] = {a4.x, a4.y, a4.z, a4.w};
      float bv_[4] = {b4.x, b4.y, b4.z, b4.w};
#pragma unroll
      for (int i = 0; i < 4; ++i)
#pragma unroll
        for (int j = 0; j < 4; ++j) acc[i][j] += av_[i] * bv_[j];
    }
    __syncthreads();
  }
  float4 bb = *(const float4*)(bias + col0 + tn);
  float bv_[4] = {bb.x, bb.y, bb.z, bb.w};
#pragma unroll
  for (int i = 0; i < 4; ++i) {
    float4 o;
    o.x = acc[i][0] + bv_[0];
    o.y = acc[i][1] + bv_[1];
    o.z = acc[i][2] + bv_[2];
    o.w = acc[i][3] + bv_[3];
    *(float4*)(Y + (size_t)(row0 + tm + i) * DIM + col0 + tn) = o;
  }
}

// ---------------------------------------------------------------------------
// inv_norm[row] = rsqrt(max(sum(s^2), 1e-10))
// ---------------------------------------------------------------------------
__global__ __launch_bounds__(256) void norm_kernel(const float* __restrict__ s,
                                                   float* __restrict__ inv_norm) {
  const int row = blockIdx.x;
  const float* p = s + (size_t)row * DIM;
  const int d0 = threadIdx.x * 8;
  float4 a = *(const float4*)(p + d0);
  float4 b = *(const float4*)(p + d0 + 4);
  float sum = a.x * a.x + a.y * a.y + a.z * a.z + a.w * a.w +
              b.x * b.x + b.y * b.y + b.z * b.z + b.w * b.w;
#pragma unroll
  for (int off = 32; off; off >>= 1) sum += __shfl_down(sum, off, 64);
  __shared__ float red[4];
  if ((threadIdx.x & 63) == 0) red[threadIdx.x >> 6] = sum;
  __syncthreads();
  if (threadIdx.x == 0) {
    float tot = red[0] + red[1] + red[2] + red[3];
    inv_norm[row] = rsqrtf(fmaxf(tot, 1e-10f));
  }
}

// ---------------------------------------------------------------------------
// sim[b][m][n] = (q_b[m] . s_b[n]) * inv_norm[b*100+n]
// ---------------------------------------------------------------------------
__global__ __launch_bounds__(256) void sim_kernel(const float* __restrict__ q,
                                                  const float* __restrict__ s,
                                                  const float* __restrict__ inv_norm,
                                                  float* __restrict__ sim) {
  __shared__ float As[16][64];
  __shared__ float Bs[16][64];
  const int t = threadIdx.x;
  const int b = blockIdx.z;
  const int row0 = blockIdx.y * 64;
  const int col0 = blockIdx.x * 64;
  const float* qb = q + (size_t)b * NQ * DIM;
  const float* sb = s + (size_t)b * NS * DIM;
  const int am = t >> 2, ak = (t & 3) * 4;
  const int tm = (t >> 4) * 4, tn = (t & 15) * 4;
  float acc[4][4] = {};
  for (int k0 = 0; k0 < DIM; k0 += 16) {
    float4 av = make_float4(0.f, 0.f, 0.f, 0.f);
    if (row0 + am < NQ)
      av = *(const float4*)(qb + (size_t)(row0 + am) * DIM + k0 + ak);
    As[ak + 0][am] = av.x;
    As[ak + 1][am] = av.y;
    As[ak + 2][am] = av.z;
    As[ak + 3][am] = av.w;
    float4 bv = make_float4(0.f, 0.f, 0.f, 0.f);
    if (col0 + am < NS)
      bv = *(const float4*)(sb + (size_t)(col0 + am) * DIM + k0 + ak);
    Bs[ak + 0][am] = bv.x;
    Bs[ak + 1][am] = bv.y;
    Bs[ak + 2][am] = bv.z;
    Bs[ak + 3][am] = bv.w;
    __syncthreads();
#pragma unroll
    for (int k = 0; k < 16; ++k) {
      float4 a4 = *(const float4*)&As[k][tm];
      float4 b4 = *(const float4*)&Bs[k][tn];
      float av_[4] = {a4.x, a4.y, a4.z, a4.w};
      float bv_[4] = {b4.x, b4.y, b4.z, b4.w};
#pragma unroll
      for (int i = 0; i < 4; ++i)
#pragma unroll
        for (int j = 0; j < 4; ++j) acc[i][j] += av_[i] * bv_[j];
    }
    __syncthreads();
  }
#pragma unroll
  for (int i = 0; i < 4; ++i) {
    int m = row0 + tm + i;
    if (m >= NQ) continue;
#pragma unroll
    for (int j = 0; j < 4; ++j) {
      int n = col0 + tn + j;
      if (n >= NS) continue;
      sim[((size_t)b * NQ + m) * NS + n] = acc[i][j] * inv_norm[b * NS + n];
    }
  }
}

// ---------------------------------------------------------------------------
// softmax(100) -> one-hot contract (20) -> probs + argmax(pred as float)
// ---------------------------------------------------------------------------
__global__ __launch_bounds__(256) void softmax_kernel(
    const float* __restrict__ sim, const float* __restrict__ onehot,
    float* __restrict__ out) {
  const int wave = threadIdx.x >> 6;
  const int lane = threadIdx.x & 63;
  const int r = blockIdx.x * 4 + wave;
  const int b = r / NQ;
  const float* srow = sim + (size_t)r * NS;
  float v1 = srow[lane];
  float v2 = (lane < NS - 64) ? srow[lane + 64] : -INFINITY;
  float m = fmaxf(v1, v2);
#pragma unroll
  for (int off = 32; off; off >>= 1) m = fmaxf(m, __shfl_xor(m, off, 64));
  float e1 = expf(v1 - m);
  float e2 = (lane < NS - 64) ? expf(v2 - m) : 0.f;
  float ssum = e1 + e2;
#pragma unroll
  for (int off = 32; off; off >>= 1) ssum += __shfl_xor(ssum, off, 64);
  float inv = 1.0f / ssum;
  __shared__ float att[4][NS];
  __shared__ float pr[4][NCLS];
  att[wave][lane] = e1 * inv;
  if (lane < NS - 64) att[wave][lane + 64] = e2 * inv;
  __syncthreads();
  if (lane < NCLS) {
    const float* oh = onehot + ((size_t)b * NS) * NCLS + lane;
    float p = 0.f;
#pragma unroll 4
    for (int j = 0; j < NS; ++j) p += att[wave][j] * oh[(size_t)j * NCLS];
    out[(size_t)r * NCLS + lane] = p;
    pr[wave][lane] = p;
  }
  __syncthreads();
  if (lane == 0) {
    int best = 0;
    float bv = pr[wave][0];
    for (int c = 1; c < NCLS; ++c) {
      float v = pr[wave][c];
      if (v > bv) { bv = v; best = c; }
    }
    out[(size_t)MQ * NCLS + r] = (float)best;
  }
}

// ---------------------------------------------------------------------------
extern "C" void kernel_launch(void* const* d_in, const int* in_sizes, int n_in,
                              void* d_out, int out_size, void* d_ws,
                              size_t ws_size, hipStream_t stream) {
  const float* support = (const float*)d_in[0];
  const float* query   = (const float*)d_in[1];
  const float* onehot  = (const float*)d_in[2];
  const float* W       = (const float*)d_in[3];
  const float* bias    = (const float*)d_in[4];

  char* wsb = (char*)d_ws;
  float* s = (float*)wsb;                       // 6400*2048*4  = 52,428,800
  float* q = (float*)(wsb + (size_t)52428800);  // 19200*2048*4 = 157,286,400

  // s+q end at 209,715,200; W1/W2/W3 bf16 splits 8,388,608 each
  const size_t FAST3 = 234881024;  // 224 MiB (known to fit from R3)

  if (ws_size >= FAST3) {
    unsigned short* W1 = (unsigned short*)(wsb + (size_t)209715200);
    unsigned short* W2 = (unsigned short*)(wsb + (size_t)218103808);
    unsigned short* W3 = (unsigned short*)(wsb + (size_t)226492416);
    // sim + inv_norm alias the W1 region (splits dead after the gemms)
    float* sim      = (float*)(wsb + (size_t)209715200);
    float* inv_norm = (float*)(wsb + (size_t)209715200 + (size_t)MQ * NS * 4);

    wsplit3<<<dim3(DIM / 64, DIM / 64), 256, 0, stream>>>(W, W1, W2, W3);
    gemm_mfma5<<<dim3(DIM / 256, MS / 128), 256, 0, stream>>>(support, W1, W2,
                                                              W3, bias, s);
    gemm_mfma5<<<dim3(DIM / 256, MQ / 128), 256, 0, stream>>>(query, W1, W2,
                                                              W3, bias, q);
    norm_kernel<<<MS, 256, 0, stream>>>(s, inv_norm);
    sim_kernel<<<dim3(2, 5, BATCH), 256, 0, stream>>>(q, s, inv_norm, sim);
    softmax_kernel<<<MQ / 4, 256, 0, stream>>>(sim, onehot, (float*)d_out);
  } else {
    // proven R1 fallback (fits in 217.5 MB)
    float* inv_norm = q + (size_t)MQ * DIM;
    float* sim      = inv_norm + MS;
    gemm_xw<<<dim3(MS / 64, DIM / 64), 256, 0, stream>>>(support, W, bias, s);
    gemm_xw<<<dim3(MQ / 64, DIM / 64), 256, 0, stream>>>(query, W, bias, q);
    norm_kernel<<<MS, 256, 0, stream>>>(s, inv_norm);
    sim_kernel<<<dim3(2, 5, BATCH), 256, 0, stream>>>(q, s, inv_norm, sim);
    softmax_kernel<<<MQ / 4, 256, 0, stream>>>(sim, onehot, (float*)d_out);
  }
}

// Round 5
// 1380.107 us; speedup vs baseline: 2.4521x; 1.1760x over previous
//
#include <hip/hip_runtime.h>
#include <hip/hip_bf16.h>
#include <math.h>

// Problem constants: B=64, C=20, K=5, Q=15, D=2048
#define BATCH 64
#define NCLS  20
#define NS    100   // C*K
#define NQ    300   // C*Q
#define DIM   2048
#define MS    (BATCH * NS)   // 6400
#define MQ    (BATCH * NQ)   // 19200

typedef __attribute__((ext_vector_type(8))) short frag_ab;   // 8 bf16 (4 VGPRs)
typedef __attribute__((ext_vector_type(4))) float frag_cd;   // 4 fp32 acc

union FAB { frag_ab f; unsigned u[4]; };

// round-to-nearest-even bf16 hi part, returned as fp32 bit pattern
__device__ __forceinline__ unsigned rne_hi(float x) {
  unsigned u = __float_as_uint(x);
  return (u + 0x7FFFu + ((u >> 16) & 1u)) & 0xFFFF0000u;
}

// 2-level RNE split of pair (x,y): x ~= x1 + x2, |residual| <= 2^-18|x|.
// p1/p2 are packed bf16x2 (low short = x, high short = y) matching MFMA
// A-operand layout (k even in low half).
__device__ __forceinline__ void split2rn(float x, float y, unsigned& p1,
                                         unsigned& p2) {
  union { __hip_bfloat162 h; unsigned u; } c1, c2;
  c1.h = __float22bfloat162_rn(make_float2(x, y));
  p1 = c1.u;
  float rx = x - __uint_as_float(c1.u << 16);
  float ry = y - __uint_as_float(c1.u & 0xFFFF0000u);
  c2.h = __float22bfloat162_rn(make_float2(rx, ry));
  p2 = c2.u;
}

#define GLL16(g, l)                                                            \
  __builtin_amdgcn_global_load_lds(                                            \
      (const __attribute__((address_space(1))) void*)(g),                      \
      (__attribute__((address_space(3))) void*)(l), 16, 0, 0)

// ---------------------------------------------------------------------------
// W [k][n] fp32 -> W1/W2 [n][k] bf16, 2-level RNE split (hi+mid, res ~2^-18)
// grid (32,32), 64x64 tile transpose via LDS.
// ---------------------------------------------------------------------------
__global__ __launch_bounds__(256) void wsplit2(const float* __restrict__ W,
                                               unsigned short* __restrict__ W1,
                                               unsigned short* __restrict__ W2) {
  __shared__ float T[64][65];
  const int k0 = blockIdx.x * 64, n0 = blockIdx.y * 64;
  const int r = threadIdx.x >> 4, c = (threadIdx.x & 15) * 4;
#pragma unroll
  for (int p = 0; p < 4; ++p) {
    float4 v = *(const float4*)&W[(size_t)(k0 + p * 16 + r) * DIM + n0 + c];
    T[p * 16 + r][c + 0] = v.x;
    T[p * 16 + r][c + 1] = v.y;
    T[p * 16 + r][c + 2] = v.z;
    T[p * 16 + r][c + 3] = v.w;
  }
  __syncthreads();
#pragma unroll
  for (int p = 0; p < 4; ++p) {
    int n = p * 16 + r;
    ushort4 o1, o2;
    unsigned short* d1 = (unsigned short*)&o1;
    unsigned short* d2 = (unsigned short*)&o2;
#pragma unroll
    for (int qq = 0; qq < 4; ++qq) {
      float x = T[c + qq][n];
      unsigned u1 = rne_hi(x);
      float r1 = x - __uint_as_float(u1);
      unsigned u2 = rne_hi(r1);
      d1[qq] = (unsigned short)(u1 >> 16);
      d2[qq] = (unsigned short)(u2 >> 16);
    }
    *(ushort4*)&W1[(size_t)(n0 + n) * DIM + k0 + c] = o1;
    *(ushort4*)&W2[(size_t)(n0 + n) * DIM + k0 + c] = o2;
  }
}

// ---------------------------------------------------------------------------
// MFMA split GEMM, 3 terms: Y = X @ W + bias.
// Block tile 128(M) x 256(N), BK=32, 4 waves 2x2 over 128x128 half, 2 column
// halves. A: 2-level RNE split in regs. B: pre-split W1/W2 [n][k].
// Terms a1b1 + a1b2 + a2b1; dropped (a2b2, a1b3, ra*b) are ~2^-18 relative,
// zero-mean sign-symmetric -> sqrt(K) accumulation, fp32-class for argmax.
// ---------------------------------------------------------------------------
__global__ __launch_bounds__(256, 2) void gemm_mfma3t(
    const float* __restrict__ X, const unsigned short* __restrict__ W1,
    const unsigned short* __restrict__ W2, const float* __restrict__ bias,
    float* __restrict__ Y) {
  __shared__ __align__(16) float          As[4][2][128][4];  // 16KB
  __shared__ __align__(16) unsigned short B1[4][256][8];     // 16KB
  __shared__ __align__(16) unsigned short B2[4][256][8];     // 16KB

  const int tid = threadIdx.x;
  const int w = tid >> 6, lane = tid & 63;
  const int ml = lane & 15, kq = lane >> 4;
  const int wm = (w >> 1) * 64, wn = (w & 1) * 64;
  const int col0 = blockIdx.x * 256, row0 = blockIdx.y * 128;

  frag_cd acc[2][4][4];
#pragma unroll
  for (int h = 0; h < 2; ++h)
#pragma unroll
    for (int i = 0; i < 4; ++i)
#pragma unroll
      for (int j = 0; j < 4; ++j)
#pragma unroll
        for (int r = 0; r < 4; ++r) acc[h][i][j][r] = 0.f;

  for (int k0 = 0; k0 < DIM; k0 += 32) {
    // ---- stage A (fp32): wave w covers kq=w ----
#pragma unroll
    for (int h = 0; h < 2; ++h)
#pragma unroll
      for (int mh = 0; mh < 2; ++mh) {
        const float* g =
            X + (size_t)(row0 + mh * 64 + lane) * DIM + k0 + w * 8 + h * 4;
        GLL16(g, &As[w][h][mh * 64][0]);
      }
    // ---- stage B (2 splits x 256 cols): wave w covers kq=w ----
#pragma unroll
    for (int t = 0; t < 4; ++t) {
      const size_t off = (size_t)(col0 + t * 64 + lane) * DIM + k0 + w * 8;
      GLL16(W1 + off, &B1[w][t * 64][0]);
      GLL16(W2 + off, &B2[w][t * 64][0]);
    }
    __syncthreads();

    // ---- A frags: fp32 -> 2-level RNE split (once per k-tile) ----
    FAB a1[4], a2[4];
#pragma unroll
    for (int i = 0; i < 4; ++i) {
      int m = wm + i * 16 + ml;
      float4 f0 = *(const float4*)&As[kq][0][m][0];  // k = kq*8 + 0..3
      float4 f1 = *(const float4*)&As[kq][1][m][0];  // k = kq*8 + 4..7
      split2rn(f0.x, f0.y, a1[i].u[0], a2[i].u[0]);
      split2rn(f0.z, f0.w, a1[i].u[1], a2[i].u[1]);
      split2rn(f1.x, f1.y, a1[i].u[2], a2[i].u[2]);
      split2rn(f1.z, f1.w, a1[i].u[3], a2[i].u[3]);
    }
    // ---- 2 column halves x 16 frag-pairs x 3 MFMA terms ----
#pragma unroll
    for (int nh = 0; nh < 2; ++nh) {
#pragma unroll
      for (int j = 0; j < 4; ++j) {
        int n = nh * 128 + wn + j * 16 + ml;
        FAB b1, b2;
        *(uint4*)&b1.u[0] = *(const uint4*)&B1[kq][n][0];
        *(uint4*)&b2.u[0] = *(const uint4*)&B2[kq][n][0];
#pragma unroll
        for (int i = 0; i < 4; ++i) {
          acc[nh][i][j] = __builtin_amdgcn_mfma_f32_16x16x32_bf16(
              a1[i].f, b1.f, acc[nh][i][j], 0, 0, 0);
          acc[nh][i][j] = __builtin_amdgcn_mfma_f32_16x16x32_bf16(
              a1[i].f, b2.f, acc[nh][i][j], 0, 0, 0);
          acc[nh][i][j] = __builtin_amdgcn_mfma_f32_16x16x32_bf16(
              a2[i].f, b1.f, acc[nh][i][j], 0, 0, 0);
        }
      }
    }
    __syncthreads();
  }

  // ---- epilogue: C/D layout col=lane&15, row=(lane>>4)*4+reg ----
#pragma unroll
  for (int nh = 0; nh < 2; ++nh)
#pragma unroll
    for (int j = 0; j < 4; ++j) {
      int col = col0 + nh * 128 + wn + j * 16 + ml;
      float bv = bias[col];
#pragma unroll
      for (int i = 0; i < 4; ++i) {
        int rowb = row0 + wm + i * 16 + kq * 4;
#pragma unroll
        for (int r = 0; r < 4; ++r)
          Y[(size_t)(rowb + r) * DIM + col] = acc[nh][i][j][r] + bv;
      }
    }
}

// ---------------------------------------------------------------------------
// Fallback fp32 GEMM (proven R1 path, used only if ws_size is too small)
// ---------------------------------------------------------------------------
__global__ __launch_bounds__(256) void gemm_xw(const float* __restrict__ X,
                                               const float* __restrict__ W,
                                               const float* __restrict__ bias,
                                               float* __restrict__ Y) {
  __shared__ float As[16][64];
  __shared__ float Bs[16][64];
  const int t = threadIdx.x;
  const int row0 = blockIdx.x * 64;
  const int col0 = blockIdx.y * 64;
  const int am = t >> 2, ak = (t & 3) * 4;
  const int bk = t >> 4, bn = (t & 15) * 4;
  const int tm = (t >> 4) * 4, tn = (t & 15) * 4;
  float acc[4][4] = {};
  for (int k0 = 0; k0 < DIM; k0 += 16) {
    float4 av = *(const float4*)(X + (size_t)(row0 + am) * DIM + k0 + ak);
    As[ak + 0][am] = av.x;
    As[ak + 1][am] = av.y;
    As[ak + 2][am] = av.z;
    As[ak + 3][am] = av.w;
    *(float4*)&Bs[bk][bn] =
        *(const float4*)(W + (size_t)(k0 + bk) * DIM + col0 + bn);
    __syncthreads();
#pragma unroll
    for (int k = 0; k < 16; ++k) {
      float4 a4 = *(const float4*)&As[k][tm];
      float4 b4 = *(const float4*)&Bs[k][tn];
      float av_[4] = {a4.x, a4.y, a4.z, a4.w};
      float bv_[4] = {b4.x, b4.y, b4.z, b4.w};
#pragma unroll
      for (int i = 0; i < 4; ++i)
#pragma unroll
        for (int j = 0; j < 4; ++j) acc[i][j] += av_[i] * bv_[j];
    }
    __syncthreads();
  }
  float4 bb = *(const float4*)(bias + col0 + tn);
  float bv_[4] = {bb.x, bb.y, bb.z, bb.w};
#pragma unroll
  for (int i = 0; i < 4; ++i) {
    float4 o;
    o.x = acc[i][0] + bv_[0];
    o.y = acc[i][1] + bv_[1];
    o.z = acc[i][2] + bv_[2];
    o.w = acc[i][3] + bv_[3];
    *(float4*)(Y + (size_t)(row0 + tm + i) * DIM + col0 + tn) = o;
  }
}

// ---------------------------------------------------------------------------
// inv_norm[row] = rsqrt(max(sum(s^2), 1e-10))
// ---------------------------------------------------------------------------
__global__ __launch_bounds__(256) void norm_kernel(const float* __restrict__ s,
                                                   float* __restrict__ inv_norm) {
  const int row = blockIdx.x;
  const float* p = s + (size_t)row * DIM;
  const int d0 = threadIdx.x * 8;
  float4 a = *(const float4*)(p + d0);
  float4 b = *(const float4*)(p + d0 + 4);
  float sum = a.x * a.x + a.y * a.y + a.z * a.z + a.w * a.w +
              b.x * b.x + b.y * b.y + b.z * b.z + b.w * b.w;
#pragma unroll
  for (int off = 32; off; off >>= 1) sum += __shfl_down(sum, off, 64);
  __shared__ float red[4];
  if ((threadIdx.x & 63) == 0) red[threadIdx.x >> 6] = sum;
  __syncthreads();
  if (threadIdx.x == 0) {
    float tot = red[0] + red[1] + red[2] + red[3];
    inv_norm[row] = rsqrtf(fmaxf(tot, 1e-10f));
  }
}

// ---------------------------------------------------------------------------
// sim[b][m][n] = (q_b[m] . s_b[n]) * inv_norm[b*100+n]
// ---------------------------------------------------------------------------
__global__ __launch_bounds__(256) void sim_kernel(const float* __restrict__ q,
                                                  const float* __restrict__ s,
                                                  const float* __restrict__ inv_norm,
                                                  float* __restrict__ sim) {
  __shared__ float As[16][64];
  __shared__ float Bs[16][64];
  const int t = threadIdx.x;
  const int b = blockIdx.z;
  const int row0 = blockIdx.y * 64;
  const int col0 = blockIdx.x * 64;
  const float* qb = q + (size_t)b * NQ * DIM;
  const float* sb = s + (size_t)b * NS * DIM;
  const int am = t >> 2, ak = (t & 3) * 4;
  const int tm = (t >> 4) * 4, tn = (t & 15) * 4;
  float acc[4][4] = {};
  for (int k0 = 0; k0 < DIM; k0 += 16) {
    float4 av = make_float4(0.f, 0.f, 0.f, 0.f);
    if (row0 + am < NQ)
      av = *(const float4*)(qb + (size_t)(row0 + am) * DIM + k0 + ak);
    As[ak + 0][am] = av.x;
    As[ak + 1][am] = av.y;
    As[ak + 2][am] = av.z;
    As[ak + 3][am] = av.w;
    float4 bv = make_float4(0.f, 0.f, 0.f, 0.f);
    if (col0 + am < NS)
      bv = *(const float4*)(sb + (size_t)(col0 + am) * DIM + k0 + ak);
    Bs[ak + 0][am] = bv.x;
    Bs[ak + 1][am] = bv.y;
    Bs[ak + 2][am] = bv.z;
    Bs[ak + 3][am] = bv.w;
    __syncthreads();
#pragma unroll
    for (int k = 0; k < 16; ++k) {
      float4 a4 = *(const float4*)&As[k][tm];
      float4 b4 = *(const float4*)&Bs[k][tn];
      float av_[4] = {a4.x, a4.y, a4.z, a4.w};
      float bv_[4] = {b4.x, b4.y, b4.z, b4.w};
#pragma unroll
      for (int i = 0; i < 4; ++i)
#pragma unroll
        for (int j = 0; j < 4; ++j) acc[i][j] += av_[i] * bv_[j];
    }
    __syncthreads();
  }
#pragma unroll
  for (int i = 0; i < 4; ++i) {
    int m = row0 + tm + i;
    if (m >= NQ) continue;
#pragma unroll
    for (int j = 0; j < 4; ++j) {
      int n = col0 + tn + j;
      if (n >= NS) continue;
      sim[((size_t)b * NQ + m) * NS + n] = acc[i][j] * inv_norm[b * NS + n];
    }
  }
}

// ---------------------------------------------------------------------------
// softmax(100) -> one-hot contract (20) -> probs + argmax(pred as float)
// ---------------------------------------------------------------------------
__global__ __launch_bounds__(256) void softmax_kernel(
    const float* __restrict__ sim, const float* __restrict__ onehot,
    float* __restrict__ out) {
  const int wave = threadIdx.x >> 6;
  const int lane = threadIdx.x & 63;
  const int r = blockIdx.x * 4 + wave;
  const int b = r / NQ;
  const float* srow = sim + (size_t)r * NS;
  float v1 = srow[lane];
  float v2 = (lane < NS - 64) ? srow[lane + 64] : -INFINITY;
  float m = fmaxf(v1, v2);
#pragma unroll
  for (int off = 32; off; off >>= 1) m = fmaxf(m, __shfl_xor(m, off, 64));
  float e1 = expf(v1 - m);
  float e2 = (lane < NS - 64) ? expf(v2 - m) : 0.f;
  float ssum = e1 + e2;
#pragma unroll
  for (int off = 32; off; off >>= 1) ssum += __shfl_xor(ssum, off, 64);
  float inv = 1.0f / ssum;
  __shared__ float att[4][NS];
  __shared__ float pr[4][NCLS];
  att[wave][lane] = e1 * inv;
  if (lane < NS - 64) att[wave][lane + 64] = e2 * inv;
  __syncthreads();
  if (lane < NCLS) {
    const float* oh = onehot + ((size_t)b * NS) * NCLS + lane;
    float p = 0.f;
#pragma unroll 4
    for (int j = 0; j < NS; ++j) p += att[wave][j] * oh[(size_t)j * NCLS];
    out[(size_t)r * NCLS + lane] = p;
    pr[wave][lane] = p;
  }
  __syncthreads();
  if (lane == 0) {
    int best = 0;
    float bv = pr[wave][0];
    for (int c = 1; c < NCLS; ++c) {
      float v = pr[wave][c];
      if (v > bv) { bv = v; best = c; }
    }
    out[(size_t)MQ * NCLS + r] = (float)best;
  }
}

// ---------------------------------------------------------------------------
extern "C" void kernel_launch(void* const* d_in, const int* in_sizes, int n_in,
                              void* d_out, int out_size, void* d_ws,
                              size_t ws_size, hipStream_t stream) {
  const float* support = (const float*)d_in[0];
  const float* query   = (const float*)d_in[1];
  const float* onehot  = (const float*)d_in[2];
  const float* W       = (const float*)d_in[3];
  const float* bias    = (const float*)d_in[4];

  char* wsb = (char*)d_ws;
  float* s = (float*)wsb;                       // 6400*2048*4  = 52,428,800
  float* q = (float*)(wsb + (size_t)52428800);  // 19200*2048*4 = 157,286,400

  // s+q end at 209,715,200; W1/W2 bf16 splits 8,388,608 each
  const size_t FAST = 226492416;  // < 224 MiB gate that passed in R3/R4

  if (ws_size >= FAST) {
    unsigned short* W1 = (unsigned short*)(wsb + (size_t)209715200);
    unsigned short* W2 = (unsigned short*)(wsb + (size_t)218103808);
    // sim + inv_norm alias the W1 region (splits dead after the gemms)
    float* sim      = (float*)(wsb + (size_t)209715200);
    float* inv_norm = (float*)(wsb + (size_t)209715200 + (size_t)MQ * NS * 4);

    wsplit2<<<dim3(DIM / 64, DIM / 64), 256, 0, stream>>>(W, W1, W2);
    gemm_mfma3t<<<dim3(DIM / 256, MS / 128), 256, 0, stream>>>(support, W1, W2,
                                                               bias, s);
    gemm_mfma3t<<<dim3(DIM / 256, MQ / 128), 256, 0, stream>>>(query, W1, W2,
                                                               bias, q);
    norm_kernel<<<MS, 256, 0, stream>>>(s, inv_norm);
    sim_kernel<<<dim3(2, 5, BATCH), 256, 0, stream>>>(q, s, inv_norm, sim);
    softmax_kernel<<<MQ / 4, 256, 0, stream>>>(sim, onehot, (float*)d_out);
  } else {
    // proven R1 fallback (fits in 217.5 MB)
    float* inv_norm = q + (size_t)MQ * DIM;
    float* sim      = inv_norm + MS;
    gemm_xw<<<dim3(MS / 64, DIM / 64), 256, 0, stream>>>(support, W, bias, s);
    gemm_xw<<<dim3(MQ / 64, DIM / 64), 256, 0, stream>>>(query, W, bias, q);
    norm_kernel<<<MS, 256, 0, stream>>>(s, inv_norm);
    sim_kernel<<<dim3(2, 5, BATCH), 256, 0, stream>>>(q, s, inv_norm, sim);
    softmax_kernel<<<MQ / 4, 256, 0, stream>>>(sim, onehot, (float*)d_out);
  }
}